// Round 3
// baseline (485.552 us; speedup 1.0000x reference)
//
#include <hip/hip_runtime.h>

#define DIM   1024
#define SEQ   2048
#define NH    16
#define HD    64

typedef __attribute__((ext_vector_type(8))) short frag_ab;
typedef __attribute__((ext_vector_type(4))) short bf16x4;
typedef __attribute__((ext_vector_type(4))) float f32x4;

__device__ __forceinline__ ushort f32_bf16_rne(float f) {
  union { float f; unsigned int u; } v; v.f = f;
  unsigned int u = v.u + 0x7FFFu + ((v.u >> 16) & 1u);
  return (ushort)(u >> 16);
}

__device__ __forceinline__ void split_bf16(float f, ushort& h, ushort& l) {
  h = f32_bf16_rne(f);
  union { unsigned int u; float f; } hv; hv.u = ((unsigned int)h) << 16;
  l = f32_bf16_rne(f - hv.f);
}

__device__ __forceinline__ void gl2lds16(const void* g, void* l) {
  __builtin_amdgcn_global_load_lds(
      (const __attribute__((address_space(1))) unsigned int*)g,
      (__attribute__((address_space(3))) unsigned int*)l, 16, 0, 0);
}

__device__ __forceinline__ float asfloat(unsigned int u) {
  union { unsigned int u; float f; } v; v.u = u; return v.f;
}

// PV MFMA: 16x16x16 bf16 (K=16). B-operand layout (k=4*quad+j, n=ml) matches
// the C-layout of the S^T score tiles -> P stays in registers.
#if __has_builtin(__builtin_amdgcn_mfma_f32_16x16x16bf16_1k)
__device__ __forceinline__ f32x4 mfma16(bf16x4 a, bf16x4 b, f32x4 c) {
  return __builtin_amdgcn_mfma_f32_16x16x16bf16_1k(a, b, c, 0, 0, 0);
}
#elif __has_builtin(__builtin_amdgcn_mfma_f32_16x16x16_bf16)
__device__ __forceinline__ f32x4 mfma16(bf16x4 a, bf16x4 b, f32x4 c) {
  return __builtin_amdgcn_mfma_f32_16x16x16_bf16(a, b, c, 0, 0, 0);
}
#else
__device__ __forceinline__ f32x4 mfma16(bf16x4 a, bf16x4 b, f32x4 c) {
  f32x4 d;
  asm volatile("v_mfma_f32_16x16x16_bf16 %0, %1, %2, %3"
               : "=v"(d) : "v"(a), "v"(b), "v"(c));
  return d;
}
#endif

// ---------------------------------------------------------------------------
// cast_x: fp32 -> bf16 copy.
// ---------------------------------------------------------------------------
__global__ __launch_bounds__(256) void cast_x(const float* __restrict__ x,
                                              ushort* __restrict__ xb) {
  int i = (blockIdx.x * 256 + threadIdx.x) * 8;
  float4 a = *(const float4*)(x + i);
  float4 b = *(const float4*)(x + i + 4);
  uint4 o;
  o.x = (unsigned int)f32_bf16_rne(a.x) | ((unsigned int)f32_bf16_rne(a.y) << 16);
  o.y = (unsigned int)f32_bf16_rne(a.z) | ((unsigned int)f32_bf16_rne(a.w) << 16);
  o.z = (unsigned int)f32_bf16_rne(b.x) | ((unsigned int)f32_bf16_rne(b.y) << 16);
  o.w = (unsigned int)f32_bf16_rne(b.z) | ((unsigned int)f32_bf16_rne(b.w) << 16);
  *(uint4*)(xb + i) = o;
}

// ---------------------------------------------------------------------------
// tcast: transpose + cast W [K][N] f32 -> Wt [N][K] bf16 (opt. hi/lo split).
// ---------------------------------------------------------------------------
template <bool SPLIT>
__global__ __launch_bounds__(256) void tcast(const float* __restrict__ in,
                                             int K, int N,
                                             ushort* __restrict__ outh,
                                             ushort* __restrict__ outl) {
  __shared__ __align__(16) ushort Th[64][72];
  __shared__ __align__(16) ushort Tl[64][72];
  const int kb = blockIdx.y * 64, nb = blockIdx.x * 64;
  const int t = threadIdx.x;
  const int kr = t >> 4, nc = (t & 15) * 4;
#pragma unroll
  for (int j = 0; j < 4; ++j) {
    int k = kr + j * 16;
    float4 v = *(const float4*)&in[(size_t)(kb + k) * N + nb + nc];
    float vv[4] = {v.x, v.y, v.z, v.w};
#pragma unroll
    for (int i = 0; i < 4; ++i) {
      if (SPLIT) {
        ushort h, l; split_bf16(vv[i], h, l);
        Th[nc + i][k] = h; Tl[nc + i][k] = l;
      } else {
        Th[nc + i][k] = f32_bf16_rne(vv[i]);
      }
    }
  }
  __syncthreads();
  const int n = t >> 2, kc = (t & 3) * 16;
  *(uint4*)&outh[(size_t)(nb + n) * K + kb + kc]     = *(const uint4*)&Th[n][kc];
  *(uint4*)&outh[(size_t)(nb + n) * K + kb + kc + 8] = *(const uint4*)&Th[n][kc + 8];
  if (SPLIT) {
    *(uint4*)&outl[(size_t)(nb + n) * K + kb + kc]     = *(const uint4*)&Tl[n][kc];
    *(uint4*)&outl[(size_t)(nb + n) * K + kb + kc + 8] = *(const uint4*)&Tl[n][kc + 8];
  }
}

// ---------------------------------------------------------------------------
// qkv_mfma (round-2, verified): C = Xb @ Wqt^T (+bias) -> Q,K,V^T bf16.
// ---------------------------------------------------------------------------
__global__ __launch_bounds__(256) void qkv_mfma(
    const ushort* __restrict__ Xb, const ushort* __restrict__ Wqt,
    const float* __restrict__ bias,
    ushort* __restrict__ Qw, ushort* __restrict__ Kw, ushort* __restrict__ Vtw) {
  __shared__ __align__(16) ushort As[128 * 32];
  __shared__ __align__(16) ushort Bs[128 * 32];
  const int t = threadIdx.x, wave = t >> 6, lane = t & 63;
  const int ml = lane & 15, quad = lane >> 4;
  const int m0 = blockIdx.y * 128, n0 = blockIdx.x * 128;
  const int wm = (wave & 1) * 64, wn = (wave >> 1) * 64;
  const int srow = lane >> 2, scol = (lane & 3) * 8;
  const int r0 = wave * 16, r1 = (4 + wave) * 16;

  const ushort* Ag = Xb  + (size_t)(m0 + srow) * DIM + scol;
  const ushort* Bg = Wqt + (size_t)(n0 + srow) * DIM + scol;

  f32x4 acc[4][4];
#pragma unroll
  for (int i = 0; i < 4; ++i)
#pragma unroll
    for (int j = 0; j < 4; ++j) acc[i][j] = (f32x4){0.f, 0.f, 0.f, 0.f};

  for (int k0 = 0; k0 < DIM; k0 += 32) {
    __syncthreads();
    gl2lds16(Ag + (size_t)r0 * DIM + k0, &As[r0 * 32]);
    gl2lds16(Ag + (size_t)r1 * DIM + k0, &As[r1 * 32]);
    gl2lds16(Bg + (size_t)r0 * DIM + k0, &Bs[r0 * 32]);
    gl2lds16(Bg + (size_t)r1 * DIM + k0, &Bs[r1 * 32]);
    __syncthreads();
    frag_ab af[4], bfr[4];
#pragma unroll
    for (int im = 0; im < 4; ++im)
      af[im] = *(const frag_ab*)&As[(wm + im * 16 + ml) * 32 + quad * 8];
#pragma unroll
    for (int in_ = 0; in_ < 4; ++in_)
      bfr[in_] = *(const frag_ab*)&Bs[(wn + in_ * 16 + ml) * 32 + quad * 8];
#pragma unroll
    for (int im = 0; im < 4; ++im)
#pragma unroll
      for (int in_ = 0; in_ < 4; ++in_)
        acc[im][in_] = __builtin_amdgcn_mfma_f32_16x16x32_bf16(
            af[im], bfr[in_], acc[im][in_], 0, 0, 0);
  }

  const int t3 = n0 >> 10;
  const int b  = m0 >> 11;
  const int s0 = (m0 & (SEQ - 1)) + wm + quad * 4;
#pragma unroll
  for (int in_ = 0; in_ < 4; ++in_) {
    int n = n0 + wn + in_ * 16 + ml;
    int h = (n >> 6) & 15, d = n & 63;
    float bv = bias[n];
    size_t bh = (size_t)(b * NH + h);
    if (t3 == 2) {
#pragma unroll
      for (int im = 0; im < 4; ++im) {
        int s = s0 + im * 16;
        ushort4 v;
        v.x = f32_bf16_rne(acc[im][in_][0] + bv);
        v.y = f32_bf16_rne(acc[im][in_][1] + bv);
        v.z = f32_bf16_rne(acc[im][in_][2] + bv);
        v.w = f32_bf16_rne(acc[im][in_][3] + bv);
        *(ushort4*)&Vtw[(bh * HD + d) * SEQ + s] = v;
      }
    } else {
      ushort* dst = (t3 == 0) ? Qw : Kw;
#pragma unroll
      for (int im = 0; im < 4; ++im)
#pragma unroll
        for (int r = 0; r < 4; ++r)
          dst[(bh * SEQ + s0 + im * 16 + r) * HD + d] =
              f32_bf16_rne(acc[im][in_][r] + bv);
    }
  }
}

// ---------------------------------------------------------------------------
// attn: restructured flash attention.
//  - S^T = K·Q^T via mfma 16x16x32 (A=K tile from LDS, B=Q frags in regs)
//  - C-layout of S^T (key=4*quad+r, q=ml) == B-layout of 16x16x16 MFMA
//    -> P packed in registers (1 v_perm per pair), no LDS round-trip
//  - O^T = V^T·P^T via mfma 16x16x16 (A=V^T frags from LDS)
//  - keys split across waves (wave w owns 32 of 128 staged keys); partial O
//    and lsum reduced across waves once at the end
//  - K/V staged via global_load_lds(16B) with XOR-swizzled 16B chunks
//    (conflict-free frag reads, no padding, zero staging VALU)
//  - grid XCD-swizzled: all 32 q-tiles of one bh share blockIdx%8
// ---------------------------------------------------------------------------
__global__ __launch_bounds__(256, 3) void attn_kernel(
    const ushort* Qw, const ushort* __restrict__ Kw,
    const ushort* __restrict__ Vtw, ushort* Ohw, ushort* Olw) {
  __shared__ __align__(16) char smem[43008];
  ushort (*Qs)[72] = (ushort(*)[72])smem;        // [64][72]      @0     (9216)
  ushort* Ks = (ushort*)(smem + 9216);           // [128][64] swizzled   (16384)
  ushort* Vs = (ushort*)(smem + 25600);          // [64][128] swizzled   (16384)
  float*  lsum_buf = (float*)(smem + 41984);     // [4][64]              (1024)
  float*  Ored = (float*)(smem + 9216);          // [64][65] alias Ks/Vs (16640)

  const int t = threadIdx.x, wave = t >> 6, lane = t & 63;
  const int ml = lane & 15, quad = lane >> 4;
  const int bid = blockIdx.x;
  const int bh  = (bid & 7) | ((bid >> 8) << 3);
  const int qt0 = (bid >> 3) & 31;

  const size_t qbase = ((size_t)bh * SEQ + qt0 * 64) * HD;
  const char* Kg = (const char*)(Kw + (size_t)bh * SEQ * HD);
  const char* Vg = (const char*)(Vtw + (size_t)bh * HD * SEQ);

  // staging per-lane constants (swizzle: LDS chunk p holds global chunk p^(row&mask))
  const int krow_l = (lane >> 3) & 7;
  const int koff   = krow_l * 128 + (((lane & 7) ^ krow_l) << 4);
  const int vrow_l = lane >> 4;
  int voff[4];
#pragma unroll
  for (int i = 0; i < 4; ++i) {
    int c = (lane & 15) ^ ((i * 4 + vrow_l) & 15);
    voff[i] = (wave * 16 + i * 4 + vrow_l) * 4096 + c * 16;
  }

  // frag-read LDS addresses (ushort indices), constant over kt
  const int kaddr0 = (wave * 32 + ml) * 64 + ((quad ^ (ml & 7)) << 3);
  const int kaddr1 = (wave * 32 + ml) * 64 + (((4 + quad) ^ (ml & 7)) << 3);
  int vaddr[2];
#pragma unroll
  for (int ch = 0; ch < 2; ++ch)
    vaddr[ch] = ml * 128 + (((wave * 4 + ch * 2 + (quad >> 1)) ^ ml) << 3)
              + (quad & 1) * 4;

  // stage Q tile (once)
#pragma unroll
  for (int i = 0; i < 2; ++i) {
    int id = t * 8 + i * 2048;
    int r = id >> 6, c = id & 63;
    *(uint4*)&Qs[r][c] = *(const uint4*)(Qw + qbase + id);
  }

  f32x4 acc[4][4];
#pragma unroll
  for (int i = 0; i < 4; ++i)
#pragma unroll
    for (int j = 0; j < 4; ++j) acc[i][j] = (f32x4){0.f, 0.f, 0.f, 0.f};
  float lsum[4] = {0.f, 0.f, 0.f, 0.f};
  frag_ab qf[4][2];
  const float kscale = 0.125f * 1.4426950408889634f;  // SCALE*log2(e)

  for (int kt = 0; kt < 16; ++kt) {
    if (kt) __syncthreads();   // prior iter's frag reads done
    // DMA stage: K 128x64 (wave w -> rows w*32..w*32+31), V^T 64x128
#pragma unroll
    for (int i = 0; i < 4; ++i)
      gl2lds16(Kg + (size_t)(kt * 16384 + (wave * 32 + i * 8) * 128) + koff,
               &Ks[(wave * 32 + i * 8) * 64]);
#pragma unroll
    for (int i = 0; i < 4; ++i)
      gl2lds16(Vg + (size_t)(kt * 256) + voff[i],
               &Vs[(wave * 16 + i * 4) * 128]);
    __syncthreads();

    if (kt == 0) {
#pragma unroll
      for (int qt = 0; qt < 4; ++qt)
#pragma unroll
        for (int dc = 0; dc < 2; ++dc)
          qf[qt][dc] = *(const frag_ab*)&Qs[qt * 16 + ml][dc * 32 + quad * 8];
    }

#pragma unroll
    for (int ch = 0; ch < 2; ++ch) {
      frag_ab ak0 = *(const frag_ab*)&Ks[kaddr0 + ch * 1024];
      frag_ab ak1 = *(const frag_ab*)&Ks[kaddr1 + ch * 1024];
      bf16x4 p[4];
#pragma unroll
      for (int qt = 0; qt < 4; ++qt) {
        f32x4 sc = __builtin_amdgcn_mfma_f32_16x16x32_bf16(
            ak0, qf[qt][0], (f32x4){0.f, 0.f, 0.f, 0.f}, 0, 0, 0);
        sc = __builtin_amdgcn_mfma_f32_16x16x32_bf16(ak1, qf[qt][1], sc, 0, 0, 0);
        unsigned int u[4];
#pragma unroll
        for (int r = 0; r < 4; ++r) {
          union { float f; unsigned int u; } e;
          e.f = exp2f(fmaf(sc[r], kscale, -12.0f));
          u[r] = e.u;
        }
        // pack truncated-bf16 pairs: dword = {bf16(p_even), bf16(p_odd)}
        unsigned int d0 = __builtin_amdgcn_perm(u[1], u[0], 0x07060302u);
        unsigned int d1 = __builtin_amdgcn_perm(u[3], u[2], 0x07060302u);
        // lsum sums the SAME truncated values the MFMA consumes
        lsum[qt] += asfloat(d0 << 16) + asfloat(d0 & 0xffff0000u)
                  + asfloat(d1 << 16) + asfloat(d1 & 0xffff0000u);
        union { unsigned int i[2]; bf16x4 v; } pv;
        pv.i[0] = d0; pv.i[1] = d1;
        p[qt] = pv.v;
      }
      bf16x4 av[4];
#pragma unroll
      for (int dt = 0; dt < 4; ++dt)
        av[dt] = *(const bf16x4*)&Vs[vaddr[ch] + dt * 2048];
#pragma unroll
      for (int dt = 0; dt < 4; ++dt)
#pragma unroll
        for (int qt = 0; qt < 4; ++qt)
          acc[dt][qt] = mfma16(av[dt], p[qt], acc[dt][qt]);
    }
  }

  // lsum: reduce over quads (keys) within wave, publish per-wave totals
#pragma unroll
  for (int qt = 0; qt < 4; ++qt) {
    float s = lsum[qt];
    s += __shfl_xor(s, 16, 64);
    s += __shfl_xor(s, 32, 64);
    lsum[qt] = s;
  }
  if (quad == 0) {
#pragma unroll
    for (int qt = 0; qt < 4; ++qt) lsum_buf[wave * 64 + qt * 16 + ml] = lsum[qt];
  }
  __syncthreads();   // all compute (and Ks/Vs reads) done -> Ored may alias

  // cross-wave O reduction: wave0 stores, others atomically add
  if (wave == 0) {
#pragma unroll
    for (int dt = 0; dt < 4; ++dt)
#pragma unroll
      for (int qt = 0; qt < 4; ++qt)
#pragma unroll
        for (int r = 0; r < 4; ++r)
          Ored[(dt * 16 + quad * 4 + r) * 65 + qt * 16 + ml] = acc[dt][qt][r];
  }
  __syncthreads();
  if (wave != 0) {
#pragma unroll
    for (int dt = 0; dt < 4; ++dt)
#pragma unroll
      for (int qt = 0; qt < 4; ++qt)
#pragma unroll
        for (int r = 0; r < 4; ++r)
          atomicAdd(&Ored[(dt * 16 + quad * 4 + r) * 65 + qt * 16 + ml],
                    acc[dt][qt][r]);
  }
  __syncthreads();

  // normalize + hi/lo bf16 split, coalesced store
  const int q = t >> 2, d0 = (t & 3) * 16;
  const float inv = 1.0f / (lsum_buf[q] + lsum_buf[64 + q] +
                            lsum_buf[128 + q] + lsum_buf[192 + q]);
  size_t rowb = ((size_t)bh * SEQ + qt0 * 64 + q) * HD + d0;
#pragma unroll
  for (int g = 0; g < 2; ++g) {
    unsigned int hu[4], lu[4];
#pragma unroll
    for (int j = 0; j < 4; ++j) {
      float f0 = Ored[(d0 + g * 8 + 2 * j) * 65 + q] * inv;
      float f1 = Ored[(d0 + g * 8 + 2 * j + 1) * 65 + q] * inv;
      ushort h0, l0, h1, l1;
      split_bf16(f0, h0, l0);
      split_bf16(f1, h1, l1);
      hu[j] = (unsigned int)h0 | ((unsigned int)h1 << 16);
      lu[j] = (unsigned int)l0 | ((unsigned int)l1 << 16);
    }
    uint4 hv = {hu[0], hu[1], hu[2], hu[3]};
    uint4 lv = {lu[0], lu[1], lu[2], lu[3]};
    *(uint4*)&Ohw[rowb + g * 8] = hv;
    *(uint4*)&Olw[rowb + g * 8] = lv;
  }
}

// ---------------------------------------------------------------------------
// proj_mfma (round-2, verified): out = (Oh+Ol) @ (Wh+Wl)^T + bias.
// ---------------------------------------------------------------------------
__global__ __launch_bounds__(256) void proj_mfma(
    const ushort* __restrict__ Oh, const ushort* __restrict__ Ol,
    const ushort* __restrict__ Wph, const ushort* __restrict__ Wpl,
    const float* __restrict__ bias, float* __restrict__ out) {
  __shared__ __align__(16) ushort As[128 * 32];
  __shared__ __align__(16) ushort Bs[128 * 32];
  const int t = threadIdx.x, wave = t >> 6, lane = t & 63;
  const int ml = lane & 15, quad = lane >> 4;
  const int m0 = blockIdx.y * 128, n0 = blockIdx.x * 128;
  const int wm = (wave & 1) * 64, wn = (wave >> 1) * 64;
  const int srow = lane >> 2, scol = (lane & 3) * 8;
  const int r0 = wave * 16, r1 = (4 + wave) * 16;
  const int b = m0 >> 11, s0r = m0 & (SEQ - 1);

  f32x4 acc[4][4];
#pragma unroll
  for (int i = 0; i < 4; ++i)
#pragma unroll
    for (int j = 0; j < 4; ++j) acc[i][j] = (f32x4){0.f, 0.f, 0.f, 0.f};

  for (int kt = 0; kt < 96; ++kt) {
    int ph = kt >> 5;
    int kv = (kt & 31) * 32;
    const ushort* Asrc = (ph == 1) ? Ol : Oh;
    const ushort* Bsrc = (ph == 2) ? Wpl : Wph;
    int h = kv >> 6, dbase = kv & 63;
    const ushort* Ag = Asrc + (((size_t)(b * NH + h) * SEQ) + s0r + srow) * HD
                            + dbase + scol;
    const ushort* Bg = Bsrc + (size_t)(n0 + srow) * DIM + kv + scol;
    __syncthreads();
    gl2lds16(Ag + (size_t)r0 * HD, &As[r0 * 32]);
    gl2lds16(Ag + (size_t)r1 * HD, &As[r1 * 32]);
    gl2lds16(Bg + (size_t)r0 * DIM, &Bs[r0 * 32]);
    gl2lds16(Bg + (size_t)r1 * DIM, &Bs[r1 * 32]);
    __syncthreads();
    frag_ab af[4], bfr[4];
#pragma unroll
    for (int im = 0; im < 4; ++im)
      af[im] = *(const frag_ab*)&As[(wm + im * 16 + ml) * 32 + quad * 8];
#pragma unroll
    for (int in_ = 0; in_ < 4; ++in_)
      bfr[in_] = *(const frag_ab*)&Bs[(wn + in_ * 16 + ml) * 32 + quad * 8];
#pragma unroll
    for (int im = 0; im < 4; ++im)
#pragma unroll
      for (int in_ = 0; in_ < 4; ++in_)
        acc[im][in_] = __builtin_amdgcn_mfma_f32_16x16x32_bf16(
            af[im], bfr[in_], acc[im][in_], 0, 0, 0);
  }

#pragma unroll
  for (int in_ = 0; in_ < 4; ++in_) {
    int n = n0 + wn + in_ * 16 + ml;
    float bv = bias[n];
#pragma unroll
    for (int im = 0; im < 4; ++im)
#pragma unroll
      for (int r = 0; r < 4; ++r) {
        int m = m0 + wm + im * 16 + quad * 4 + r;
        out[(size_t)m * DIM + n] = acc[im][in_][r] + bv;
      }
  }
}

extern "C" void kernel_launch(void* const* d_in, const int* in_sizes, int n_in,
                              void* d_out, int out_size, void* d_ws, size_t ws_size,
                              hipStream_t stream) {
  const float* x      = (const float*)d_in[0];
  const float* W_qkv  = (const float*)d_in[1];
  const float* b_qkv  = (const float*)d_in[2];
  const float* W_proj = (const float*)d_in[3];
  const float* b_proj = (const float*)d_in[4];
  float* out = (float*)d_out;

  char* ws = (char*)d_ws;
  ushort* Xb  = (ushort*)(ws);
  ushort* Wqt = (ushort*)(ws + 16777216ull);
  ushort* Qw  = (ushort*)(ws + 23068672ull);
  ushort* Kw  = (ushort*)(ws + 39845888ull);
  ushort* Vtw = (ushort*)(ws + 56623104ull);
  ushort* Wph = (ushort*)(ws + 73400320ull);
  ushort* Wpl = (ushort*)(ws + 75497472ull);
  ushort* Ohw = Xb;   // Xb dead after qkv_mfma
  ushort* Olw = Qw;   // each attn block reads its Q tile before writing it

  cast_x<<<dim3(4096), 256, 0, stream>>>(x, Xb);
  tcast<false><<<dim3(48, 16), 256, 0, stream>>>(W_qkv, DIM, 3 * DIM, Wqt, nullptr);
  tcast<true><<<dim3(16, 16), 256, 0, stream>>>(W_proj, DIM, DIM, Wph, Wpl);
  qkv_mfma<<<dim3(24, 64), 256, 0, stream>>>(Xb, Wqt, b_qkv, Qw, Kw, Vtw);
  attn_kernel<<<dim3(2048), 256, 0, stream>>>(Qw, Kw, Vtw, Ohw, Olw);
  proj_mfma<<<dim3(8, 64), 256, 0, stream>>>(Ohw, Olw, Wph, Wpl, b_proj, out);
}